// Round 1
// 1484.426 us; speedup vs baseline: 1.0309x; 1.0309x over previous
//
#include <hip/hip_runtime.h>
#include <hip/hip_bf16.h>
#include <cstdint>

#define N_NODES 100000
#define N_EDGES 819200
#define D 512
#define LAYERS 3
#define LN_EPS 1e-5f

// GEMM grid geometry: 782 row-tiles x 4 col-tiles = 3128 (divisible by 8 XCDs)
#define GEMM_ROW_TILES 782
#define GEMM_GRID (GEMM_ROW_TILES * 4)
#define GEMM_CHUNK (GEMM_GRID / 8)   // 391 works per XCD

typedef __bf16 bf16x8 __attribute__((ext_vector_type(8)));
typedef float floatx4 __attribute__((ext_vector_type(4)));

// ---------- bf16 helpers ----------
__device__ __forceinline__ void bf2x2(uint32_t u, float& lo, float& hi) {
    union { uint32_t i; float f; } a, b;
    a.i = u << 16; b.i = u & 0xFFFF0000u;
    lo = a.f; hi = b.f;
}
__device__ __forceinline__ uint16_t f2bf(float f) {
    union { float f; uint32_t i; } v; v.f = f;
    uint32_t r = v.i + 0x7FFFu + ((v.i >> 16) & 1u);  // RTNE
    return (uint16_t)(r >> 16);
}
__device__ __forceinline__ uint32_t f2bf2(float lo, float hi) {
    return (uint32_t)f2bf(lo) | ((uint32_t)f2bf(hi) << 16);
}

// async global->LDS, 16B per lane (wave writes ldsbase + lane*16)
__device__ __forceinline__ void async16(const uint16_t* g, uint16_t* lds) {
    __builtin_amdgcn_global_load_lds(
        (const __attribute__((address_space(1))) uint32_t*)g,
        (__attribute__((address_space(3))) uint32_t*)lds, 16, 0, 0);
}

// ---------- CSR build ----------
__global__ void k_count(const int* __restrict__ tgt, int* __restrict__ cnt) {
    int e = blockIdx.x * blockDim.x + threadIdx.x;
    if (e < N_EDGES) atomicAdd(&cnt[tgt[e]], 1);
}

__global__ void k_scan(const int* __restrict__ cnt, int* __restrict__ row_start,
                       int* __restrict__ cursor) {
    __shared__ int wsum[16];
    const int t = threadIdx.x;
    const int lane = t & 63, wid = t >> 6;
    int running = 0;
    for (int base = 0; base < N_NODES; base += 1024) {
        int idx = base + t;
        int v = (idx < N_NODES) ? cnt[idx] : 0;
        int x = v;
        #pragma unroll
        for (int off = 1; off < 64; off <<= 1) {
            int n = __shfl_up(x, off, 64);
            if (lane >= off) x += n;
        }
        if (lane == 63) wsum[wid] = x;
        __syncthreads();
        if (wid == 0) {
            int s = (lane < 16) ? wsum[lane] : 0;
            #pragma unroll
            for (int off = 1; off < 16; off <<= 1) {
                int n = __shfl_up(s, off, 64);
                if (lane >= off) s += n;
            }
            if (lane < 16) wsum[lane] = s;
        }
        __syncthreads();
        int waveoff = (wid > 0) ? wsum[wid - 1] : 0;
        int excl = running + x + waveoff - v;
        if (idx < N_NODES) { row_start[idx] = excl; cursor[idx] = excl; }
        int chunk_total = wsum[15];
        __syncthreads();
        running += chunk_total;
    }
    if (t == 0) row_start[N_NODES] = running;
}

__global__ void k_scatter(const int* __restrict__ src, const int* __restrict__ tgt,
                          int* __restrict__ cursor, int* __restrict__ src_sorted) {
    int e = blockIdx.x * blockDim.x + threadIdx.x;
    if (e < N_EDGES) {
        int p = atomicAdd(&cursor[tgt[e]], 1);
        src_sorted[p] = src[e];
    }
}

// ---------- dtype conversion ----------
__global__ void k_f2bf(const float* __restrict__ in, uint16_t* __restrict__ out, int n) {
    int i = (blockIdx.x * blockDim.x + threadIdx.x) * 8;
    if (i < n) {
        float4 a = *(const float4*)(in + i);
        float4 b = *(const float4*)(in + i + 4);
        uint4 o;
        o.x = f2bf2(a.x, a.y); o.y = f2bf2(a.z, a.w);
        o.z = f2bf2(b.x, b.y); o.w = f2bf2(b.z, b.w);
        *(uint4*)(out + i) = o;
    }
}

__global__ void k_wcat(const float* __restrict__ Wl, const float* __restrict__ Wr,
                       uint16_t* __restrict__ wcat) {
    int i = blockIdx.x * blockDim.x + threadIdx.x;
    int k = i & 1023;
    int j = (i >> 10) & 511;
    int l = i >> 19;
    float v = (k < 512) ? Wl[((size_t)l * 512 + j) * 512 + k]
                        : Wr[((size_t)l * 512 + j) * 512 + (k - 512)];
    wcat[i] = f2bf(v);
}

// ---------- mean aggregation: one wave per node, 4-deep gather pipeline ----------
__device__ __forceinline__ void agg_acc(float* acc, uint4 p) {
    float lo, hi;
    bf2x2(p.x, lo, hi); acc[0] += lo; acc[1] += hi;
    bf2x2(p.y, lo, hi); acc[2] += lo; acc[3] += hi;
    bf2x2(p.z, lo, hi); acc[4] += lo; acc[5] += hi;
    bf2x2(p.w, lo, hi); acc[6] += lo; acc[7] += hi;
}

__global__ __launch_bounds__(256)
void k_agg(const uint16_t* __restrict__ x_bf, const int* __restrict__ row_start,
           const int* __restrict__ src_sorted, uint16_t* __restrict__ agg_bf) {
    const int wid = threadIdx.x >> 6, lane = threadIdx.x & 63;
    const int node = blockIdx.x * 4 + wid;
    if (node >= N_NODES) return;
    const int s0 = row_start[node], s1 = row_start[node + 1];
    const int col = lane * 8;
    float acc[8] = {0.f, 0.f, 0.f, 0.f, 0.f, 0.f, 0.f, 0.f};
    int e = s0;
    for (; e + 4 <= s1; e += 4) {
        int i0 = src_sorted[e], i1 = src_sorted[e + 1];
        int i2 = src_sorted[e + 2], i3 = src_sorted[e + 3];
        uint4 p0 = *(const uint4*)(x_bf + (size_t)i0 * D + col);
        uint4 p1 = *(const uint4*)(x_bf + (size_t)i1 * D + col);
        uint4 p2 = *(const uint4*)(x_bf + (size_t)i2 * D + col);
        uint4 p3 = *(const uint4*)(x_bf + (size_t)i3 * D + col);
        agg_acc(acc, p0); agg_acc(acc, p1); agg_acc(acc, p2); agg_acc(acc, p3);
    }
    if (e + 2 <= s1) {
        int i0 = src_sorted[e], i1 = src_sorted[e + 1];
        uint4 p0 = *(const uint4*)(x_bf + (size_t)i0 * D + col);
        uint4 p1 = *(const uint4*)(x_bf + (size_t)i1 * D + col);
        agg_acc(acc, p0); agg_acc(acc, p1);
        e += 2;
    }
    if (e < s1) {
        int i0 = src_sorted[e];
        uint4 p0 = *(const uint4*)(x_bf + (size_t)i0 * D + col);
        agg_acc(acc, p0);
    }
    const float inv = (s1 > s0) ? 1.0f / (float)(s1 - s0) : 0.0f;
    uint4 o;
    o.x = f2bf2(acc[0] * inv, acc[1] * inv);
    o.y = f2bf2(acc[2] * inv, acc[3] * inv);
    o.z = f2bf2(acc[4] * inv, acc[5] * inv);
    o.w = f2bf2(acc[6] * inv, acc[7] * inv);
    *(uint4*)(agg_bf + (size_t)node * D + col) = o;
}

// ---------- GEMM: h = [agg|x] @ Wcat^T, 128x128 tile, async LDS staging ----------
// LDS slot (row r, octet-slot qs) holds global k-octet q=(qs-r)&3
// -> to read octet qm of row r: slot (qm+r)&3
__device__ __forceinline__ int lds_sw(int r, int q) { return r * 32 + (((q + r) & 3) << 3); }

// __launch_bounds__(256, 4): acc[4][4] = 64 AGPR; capping arch VGPR at 64 gives
// 128 unified regs -> 4 waves/SIMD (4 blocks/CU) instead of 3 (68+64=132 regs).
__global__ __launch_bounds__(256, 4)
void k_gemm(const uint16_t* __restrict__ A0,   // agg_bf [N][512]  (k<512)
            const uint16_t* __restrict__ A1,   // x_bf   [N][512]  (k>=512)
            const uint16_t* __restrict__ W,    // wcat layer [512][1024]
            uint16_t* __restrict__ Hout)       // h_bf [N][512]
{
    __shared__ uint16_t Als[128 * 32];   // 8 KB, row-major 64B rows
    __shared__ uint16_t Wls[128 * 32];   // 8 KB
    const int tid = threadIdx.x;
    const int lane = tid & 63, wid = tid >> 6;
    const int wm = wid >> 1, wn = wid & 1;           // 2x2 wave grid, 64x64 each

    // XCD-aware swizzle (T1): default dispatch round-robins blockIdx across the
    // 8 XCDs, so the 4 col-blocks sharing one A-tile land on 4 different L2s.
    // Bijective remap (3128 % 8 == 0): XCD x executes works [x*391,(x+1)*391),
    // keeping col-siblings of a row-tile consecutive on the SAME XCD -> A-tile
    // L2 hits instead of 2x HBM re-fetch.
    const int bid = blockIdx.x;
    const int wk = (bid & 7) * GEMM_CHUNK + (bid >> 3);
    const int rb = wk >> 2, cb = wk & 3;
    const int row0 = rb * 128, col0 = cb * 128;

    // async staging: each wave issues 4 x 1KB chunks (2 A rows-16, 2 W rows-16)
    const int lr = lane >> 2, qs = lane & 3;
    const int rc0 = wid * 32 + lr;          // rows [wid*32, +16)
    const int rc1 = wid * 32 + 16 + lr;     // rows [wid*32+16, +16)
    const int q0 = (qs - rc0) & 3;          // swizzled source octet
    const int q1 = (qs - rc1) & 3;
    int gr0 = row0 + rc0; if (gr0 > N_NODES - 1) gr0 = N_NODES - 1;
    int gr1 = row0 + rc1; if (gr1 > N_NODES - 1) gr1 = N_NODES - 1;
    const size_t woff0 = (size_t)(col0 + rc0) * 1024 + q0 * 8;
    const size_t woff1 = (size_t)(col0 + rc1) * 1024 + q1 * 8;
    uint16_t* ldsA0 = &Als[(wid * 32) * 32];         // wave-uniform bases
    uint16_t* ldsA1 = &Als[(wid * 32 + 16) * 32];
    uint16_t* ldsW0 = &Wls[(wid * 32) * 32];
    uint16_t* ldsW1 = &Wls[(wid * 32 + 16) * 32];

    const int m = lane & 15;                         // frag row/col within 16
    const int qm = lane >> 4;                        // frag k-octet

    floatx4 acc[4][4] = {};

    for (int kb = 0; kb < 1024; kb += 32) {
        const uint16_t* Ab; int kl;
        if (kb < 512) { Ab = A0; kl = kb; } else { Ab = A1; kl = kb - 512; }
        async16(Ab + (size_t)gr0 * 512 + kl + q0 * 8, ldsA0);
        async16(Ab + (size_t)gr1 * 512 + kl + q1 * 8, ldsA1);
        async16(W + woff0 + kb, ldsW0);
        async16(W + woff1 + kb, ldsW1);
        __syncthreads();    // drains vmcnt -> staged tile visible

        bf16x8 af[4], bfr[4];
        #pragma unroll
        for (int mt = 0; mt < 4; mt++)
            af[mt] = *(bf16x8*)&Als[lds_sw(wm * 64 + mt * 16 + m, qm)];
        #pragma unroll
        for (int nt = 0; nt < 4; nt++)
            bfr[nt] = *(bf16x8*)&Wls[lds_sw(wn * 64 + nt * 16 + m, qm)];
        #pragma unroll
        for (int mt = 0; mt < 4; mt++)
            #pragma unroll
            for (int nt = 0; nt < 4; nt++)
                acc[mt][nt] = __builtin_amdgcn_mfma_f32_16x16x32_bf16(
                    af[mt], bfr[nt], acc[mt][nt], 0, 0, 0);
        __syncthreads();    // all reads done before next iter's async writes
    }

    // epilogue: C/D layout col=lane&15, row=(lane>>4)*4+reg  [m89-verified]
    #pragma unroll
    for (int mt = 0; mt < 4; mt++) {
        #pragma unroll
        for (int r = 0; r < 4; r++) {
            int grow = row0 + wm * 64 + mt * 16 + qm * 4 + r;
            if (grow < N_NODES) {
                #pragma unroll
                for (int nt = 0; nt < 4; nt++) {
                    int gcol = col0 + wn * 64 + nt * 16 + m;
                    Hout[(size_t)grow * 512 + gcol] = f2bf(acc[mt][nt][r]);
                }
            }
        }
    }
}

// ---------- fused bias + LayerNorm + ReLU + residual: one wave per row ----------
__global__ __launch_bounds__(256)
void k_ln(const uint16_t* __restrict__ H, const float* __restrict__ bias,
          const float* __restrict__ gam, const float* __restrict__ bet,
          uint16_t* __restrict__ xbf,     // in: residual source; out (if !last): next x
          float* __restrict__ out32, int last) {
    const int wid = threadIdx.x >> 6, lane = threadIdx.x & 63;
    const int node = blockIdx.x * 4 + wid;
    if (node >= N_NODES) return;
    const int col = lane * 8;
    const size_t off = (size_t)node * D + col;

    uint4 hp = *(const uint4*)(H + off);
    float v[8];
    bf2x2(hp.x, v[0], v[1]); bf2x2(hp.y, v[2], v[3]);
    bf2x2(hp.z, v[4], v[5]); bf2x2(hp.w, v[6], v[7]);
    float4 b0 = *(const float4*)(bias + col), b1 = *(const float4*)(bias + col + 4);
    v[0] += b0.x; v[1] += b0.y; v[2] += b0.z; v[3] += b0.w;
    v[4] += b1.x; v[5] += b1.y; v[6] += b1.z; v[7] += b1.w;

    float s = 0.f;
    #pragma unroll
    for (int i = 0; i < 8; i++) s += v[i];
    #pragma unroll
    for (int o = 32; o >= 1; o >>= 1) s += __shfl_xor(s, o, 64);
    float mu = s * (1.0f / D);
    float vs = 0.f;
    #pragma unroll
    for (int i = 0; i < 8; i++) { float d = v[i] - mu; vs += d * d; }
    #pragma unroll
    for (int o = 32; o >= 1; o >>= 1) vs += __shfl_xor(vs, o, 64);
    float rstd = rsqrtf(vs * (1.0f / D) + LN_EPS);

    float4 g0 = *(const float4*)(gam + col), g1 = *(const float4*)(gam + col + 4);
    float4 e0 = *(const float4*)(bet + col), e1 = *(const float4*)(bet + col + 4);
    float gg[8] = {g0.x, g0.y, g0.z, g0.w, g1.x, g1.y, g1.z, g1.w};
    float ee[8] = {e0.x, e0.y, e0.z, e0.w, e1.x, e1.y, e1.z, e1.w};

    uint4 xp = *(const uint4*)(xbf + off);
    float xi[8];
    bf2x2(xp.x, xi[0], xi[1]); bf2x2(xp.y, xi[2], xi[3]);
    bf2x2(xp.z, xi[4], xi[5]); bf2x2(xp.w, xi[6], xi[7]);

    float o_[8];
    #pragma unroll
    for (int i = 0; i < 8; i++) {
        float h = (v[i] - mu) * rstd * gg[i] + ee[i];
        o_[i] = fmaxf(h, 0.f) + xi[i];
    }
    if (last) {
        float4 f0 = {o_[0], o_[1], o_[2], o_[3]};
        float4 f1 = {o_[4], o_[5], o_[6], o_[7]};
        *(float4*)(out32 + off) = f0;
        *(float4*)(out32 + off + 4) = f1;
    } else {
        uint4 o;
        o.x = f2bf2(o_[0], o_[1]); o.y = f2bf2(o_[2], o_[3]);
        o.z = f2bf2(o_[4], o_[5]); o.w = f2bf2(o_[6], o_[7]);
        *(uint4*)(xbf + off) = o;
    }
}

extern "C" void kernel_launch(void* const* d_in, const int* in_sizes, int n_in,
                              void* d_out, int out_size, void* d_ws, size_t ws_size,
                              hipStream_t stream) {
    const float* x   = (const float*)d_in[0];
    const int*   ei  = (const int*)d_in[1];          // [2][N_EDGES]: src row0, tgt row1
    const float* Wl  = (const float*)d_in[2];
    const float* Wr  = (const float*)d_in[3];
    const float* b   = (const float*)d_in[4];
    const float* g   = (const float*)d_in[5];
    const float* be  = (const float*)d_in[6];
    float* out = (float*)d_out;
    const int* src = ei;
    const int* tgt = ei + N_EDGES;

    size_t off = 0;
    auto alloc = [&](size_t bytes) -> void* {
        void* p = (char*)d_ws + off;
        off += (bytes + 255) & ~(size_t)255;
        return p;
    };
    int* cnt        = (int*)alloc((size_t)N_NODES * 4);
    int* row_start  = (int*)alloc((size_t)(N_NODES + 1) * 4);
    int* cursor     = (int*)alloc((size_t)N_NODES * 4);
    int* src_sorted = (int*)alloc((size_t)N_EDGES * 4);
    uint16_t* wcat  = (uint16_t*)alloc((size_t)LAYERS * 512 * 1024 * 2);
    uint16_t* x_bf  = (uint16_t*)alloc((size_t)N_NODES * D * 2);
    uint16_t* agg_bf= (uint16_t*)alloc((size_t)N_NODES * D * 2);
    uint16_t* h_bf  = (uint16_t*)alloc((size_t)N_NODES * D * 2);

    (void)hipMemsetAsync(cnt, 0, (size_t)N_NODES * 4, stream);
    k_count<<<N_EDGES / 256, 256, 0, stream>>>(tgt, cnt);
    k_scan<<<1, 1024, 0, stream>>>(cnt, row_start, cursor);
    k_scatter<<<N_EDGES / 256, 256, 0, stream>>>(src, tgt, cursor, src_sorted);
    k_f2bf<<<(N_NODES * D / 8) / 256, 256, 0, stream>>>(x, x_bf, N_NODES * D);
    k_wcat<<<(LAYERS * 512 * 1024) / 256, 256, 0, stream>>>(Wl, Wr, wcat);

    for (int l = 0; l < LAYERS; l++) {
        k_agg<<<N_NODES / 4, 256, 0, stream>>>(x_bf, row_start, src_sorted, agg_bf);
        k_gemm<<<GEMM_GRID, 256, 0, stream>>>(agg_bf, x_bf,
                                              wcat + (size_t)l * 512 * 1024, h_bf);
        k_ln<<<N_NODES / 4, 256, 0, stream>>>(h_bf, b + l * D, g + l * D, be + l * D,
                                              x_bf, out, l == 2 ? 1 : 0);
    }
}